// Round 5
// baseline (724.408 us; speedup 1.0000x reference)
//
#include <hip/hip_runtime.h>

#define NEGV -1e30f
static constexpr int BATCH = 64;
static constexpr int NN = 512;
static constexpr int MM = 512;
static constexpr int NM = NN * MM;
static constexpr size_t TOTAL = (size_t)BATCH * NM;
static constexpr int NDIAG = NN + MM - 1;          // 1023
static constexpr size_t DBATCH = (size_t)NDIAG * NN; // diag-major floats per batch

// lane n <- lane n-1 (whole-wave shift right by 1), 1 VALU op, no LDS.
__device__ __forceinline__ float wave_shr1(float x) {
    int y = __builtin_amdgcn_mov_dpp(__float_as_int(x), 0x138, 0xf, 0xf, true);
    return __int_as_float(y);
}

// compile-time float4 component select (folds after macro expansion)
#define F4C(v, c) ((c) == 0 ? (v).x : (c) == 1 ? (v).y : (c) == 2 ? (v).z : (v).w)

// ---------------------------------------------------------------------------
// K0: skew-transpose D (row-major) -> D_diag:  Dd[b][k*512 + i] = D[b][i][k-i]
// LDS-tiled 64x64, stride 66 (read Delta = 65 === 1 mod 32: conflict-free),
// coalesced global read AND write. Slot-by-i layout => dp loads 16B-aligned.
// ---------------------------------------------------------------------------
__global__ __launch_bounds__(256) void restage_kernel(const float* __restrict__ D,
                                                      float* __restrict__ Dd) {
    __shared__ float tile[64][66];
    const int b = blockIdx.z, it = blockIdx.y, jt = blockIdx.x;
    const float* __restrict__ Db = D + (size_t)b * NM;
    float* __restrict__ Ddb = Dd + (size_t)b * DBATCH;
    const int i0 = it * 64, j0 = jt * 64;
    const int c = threadIdx.x & 63, r0 = threadIdx.x >> 6;
#pragma unroll
    for (int r = r0; r < 64; r += 4)
        tile[r][c] = Db[(size_t)(i0 + r) * MM + j0 + c];
    __syncthreads();
    for (int kk = r0; kk < 127; kk += 4) {
        const int k = i0 + j0 + kk;
        const int ilo = max(i0, k - (j0 + 63));
        const int ihi = min(i0 + 63, k - j0);
        const int i = ilo + c;
        if (i <= ihi)
            Ddb[(size_t)k * NN + i] = tile[i - i0][k - i - j0];
    }
}

// ---------------------------------------------------------------------------
// K1 (primary): wavefront DP, one wave per (batch,dir). Lane t owns rows
// [8t,8t+8). All state in named registers. D read from diag-major layout:
// per diagonal one contiguous 2KB wave-run (2 aligned float4/lane), 2-slot
// prefetch ring (compile-time slot index), ~65 VGPR => nothing to spill/sink.
// Stores row-major via 4-phase register grouping (R3 machinery, proven).
// ---------------------------------------------------------------------------
template <int DIR>
__device__ __forceinline__ void dp_run_diag(const float* __restrict__ Dd,
                                            float* __restrict__ Rp, int lane) {
    const int i0 = lane * 8;
    const bool l0 = (lane == 0);
    const float dgb0 = l0 ? 0.f : NEGV;

#define PTRS(r) \
    float* stp_##r = DIR ? (Rp + (size_t)(NM - 1) - (size_t)(i0 + r) * MM) \
                         : (Rp + (size_t)(i0 + r) * MM);
    PTRS(0) PTRS(1) PTRS(2) PTRS(3) PTRS(4) PTRS(5) PTRS(6) PTRS(7)

    // D cursors & 2-slot ring. fwd: base P = Dd + i0, diag k at P + 512k
    //   s*a = rows 0..3 (comp c -> r=c), s*b = rows 4..7 (c -> r=4+c)
    // bwd: base P = Dd + 504 - i0, orig diag K = 1022-k at P + 512K:
    //   s*a = *(P+512K+4) comp c -> r=3-c ; s*b = *(P+512K) comp c -> r=7-c
    const float* cur;
    float4 s0a, s0b, s1a, s1b;
    if (!DIR) {
        const float* P = Dd + i0;
        s0a = *(const float4*)(P);                 s0b = *(const float4*)(P + 4);
        s1a = *(const float4*)(P + NN);            s1b = *(const float4*)(P + NN + 4);
        cur = P + 2 * NN;
    } else {
        const float* P = Dd + 504 - i0;
        s0a = *(const float4*)(P + (size_t)NN * 1022 + 4); s0b = *(const float4*)(P + (size_t)NN * 1022);
        s1a = *(const float4*)(P + (size_t)NN * 1021 + 4); s1b = *(const float4*)(P + (size_t)NN * 1021);
        cur = P + (size_t)NN * 1020;
    }

#define DV(r, CA, CB) (DIR ? ((r) < 4 ? F4C(CA, 3 - (r)) : F4C(CB, 7 - (r))) \
                           : ((r) < 4 ? F4C(CA, (r)) : F4C(CB, (r) - 4)))

#define INITP(r) float p1_##r = NEGV, p2_##r = NEGV, p3_##r = NEGV, np_##r = NEGV;
    INITP(0) INITP(1) INITP(2) INITP(3) INITP(4) INITP(5) INITP(6) INITP(7)

#define CELL(r, DGIN, UPIN, DGB, CA, CB) do { \
        const int j_ = jj - (r); \
        const bool jz_ = (j_ == 0); \
        const float dg_ = jz_ ? (DGB) : (DGIN); \
        const float up_ = (UPIN); \
        const float lf_ = jz_ ? NEGV : p1_##r; \
        const float m_  = fmaxf(fmaxf(dg_, up_), lf_); \
        const float mn_ = fminf(fminf(dg_, up_), lf_); \
        const float md_ = __builtin_amdgcn_fmed3f(dg_, up_, lf_); \
        const float s_  = 1.f + __expf(mn_ - m_) + __expf(md_ - m_); \
        np_##r = DV(r, CA, CB) + m_ + __logf(s_); \
    } while (0)

#define STORE(r) do { \
        const int j_ = jj - (r); \
        if (j_ >= 3 && j_ < MM) { \
            if (DIR) *(float4*)(stp_##r - j_) = \
                make_float4(np_##r, p1_##r, p2_##r, p3_##r); \
            else     *(float4*)(stp_##r + j_ - 3) = \
                make_float4(p3_##r, p2_##r, p1_##r, np_##r); \
        } \
    } while (0)

#define SHIFT(r) do { p3_##r = p2_##r; p2_##r = p1_##r; p1_##r = np_##r; } while (0)

// one diagonal. SL = slot (kk&1) as token; SA/SB = rows at store-phase 3
#define STEP(KK, SL, SA, SB) do { \
        const int jj = kbj + (KK); \
        const float4 ca_ = s##SL##a, cb_ = s##SL##b; \
        if (!DIR) { s##SL##a = *(const float4*)(cur); \
                    s##SL##b = *(const float4*)(cur + 4); cur += NN; } \
        else      { s##SL##a = *(const float4*)(cur + 4); \
                    s##SL##b = *(const float4*)(cur); cur -= NN; } \
        const float ups_ = wave_shr1(p1_7); \
        const float dgs_ = wave_shr1(p2_7); \
        const float up0r = l0 ? NEGV : ups_; \
        const float dg0r = l0 ? NEGV : dgs_; \
        CELL(0, dg0r, up0r, dgb0, ca_, cb_); \
        CELL(1, p2_0, p1_0, NEGV, ca_, cb_); \
        CELL(2, p2_1, p1_1, NEGV, ca_, cb_); \
        CELL(3, p2_2, p1_2, NEGV, ca_, cb_); \
        CELL(4, p2_3, p1_3, NEGV, ca_, cb_); \
        CELL(5, p2_4, p1_4, NEGV, ca_, cb_); \
        CELL(6, p2_5, p1_5, NEGV, ca_, cb_); \
        CELL(7, p2_6, p1_6, NEGV, ca_, cb_); \
        STORE(SA); STORE(SB); \
        SHIFT(0); SHIFT(1); SHIFT(2); SHIFT(3); \
        SHIFT(4); SHIFT(5); SHIFT(6); SHIFT(7); \
    } while (0)

    for (int kb = 0; kb < NN + MM; kb += 4) {
        const int kbj = kb - i0;
        STEP(0, 0, 1, 5);
        STEP(1, 1, 2, 6);
        STEP(2, 0, 3, 7);
        STEP(3, 1, 0, 4);
    }
#undef PTRS
#undef DV
#undef INITP
#undef CELL
#undef STORE
#undef SHIFT
#undef STEP
}

__global__ __launch_bounds__(64, 1) void dp_kernel_diag(const float* __restrict__ Dd,
                                                        float* __restrict__ Rf,
                                                        float* __restrict__ Rb) {
    const int blk = blockIdx.x;
    const int b = blk & (BATCH - 1);
    const int dir = blk >> 6;
    const float* __restrict__ Ddb = Dd + (size_t)b * DBATCH;
    const int lane = threadIdx.x;
    if (dir) dp_run_diag<1>(Ddb, Rb + (size_t)b * NM, lane);
    else     dp_run_diag<0>(Ddb, Rf + (size_t)b * NM, lane);
}

// ---------------------------------------------------------------------------
// K1 (fallback if ws too small): R3's row-major-load version, verbatim.
// ---------------------------------------------------------------------------
template <int DIR>
__device__ __forceinline__ void dp_run_row(const float* __restrict__ Db,
                                           float* __restrict__ Rp, int lane) {
    const int i0 = lane * 8;
    const bool l0 = (lane == 0);
    const float dgb0 = l0 ? 0.f : NEGV;

#define PTRS(r) \
    const float* ldp_##r = DIR ? (Db + (size_t)(NM - 1) - (size_t)(i0 + r) * MM) \
                               : (Db + (size_t)(i0 + r) * MM); \
    float* stp_##r = DIR ? (Rp + (size_t)(NM - 1) - (size_t)(i0 + r) * MM) \
                         : (Rp + (size_t)(i0 + r) * MM);
    PTRS(0) PTRS(1) PTRS(2) PTRS(3) PTRS(4) PTRS(5) PTRS(6) PTRS(7)

#define LOADG(r, dst, jgexpr) do { \
        int jc_ = (jgexpr); \
        jc_ = jc_ < 0 ? 0 : jc_; jc_ = jc_ > (MM - 4) ? (MM - 4) : jc_; \
        if (DIR) { const float4 t_ = *(const float4*)(ldp_##r - jc_ - 3); \
                   dst = make_float4(t_.w, t_.z, t_.y, t_.x); } \
        else     { dst = *(const float4*)(ldp_##r + jc_); } \
    } while (0)

#define INIT(r) \
    float p1_##r = NEGV, p2_##r = NEGV, p3_##r = NEGV, np_##r = NEGV; \
    float4 dc_##r, dn_##r; \
    LOADG(r, dn_##r, 0); dc_##r = dn_##r;
    INIT(0) INIT(1) INIT(2) INIT(3) INIT(4) INIT(5) INIT(6) INIT(7)

#define SWAPLOAD(r) do { dc_##r = dn_##r; LOADG(r, dn_##r, jj - (r) + 4); } while (0)

#define CELL(r, KK, DGIN, UPIN, DGB) do { \
        const int j_ = jj - (r); \
        const bool jz_ = (j_ == 0); \
        const float dg_ = jz_ ? (DGB) : (DGIN); \
        const float up_ = (UPIN); \
        const float lf_ = jz_ ? NEGV : p1_##r; \
        const float m_  = fmaxf(fmaxf(dg_, up_), lf_); \
        const float mn_ = fminf(fminf(dg_, up_), lf_); \
        const float md_ = __builtin_amdgcn_fmed3f(dg_, up_, lf_); \
        const float s_  = 1.f + __expf(mn_ - m_) + __expf(md_ - m_); \
        np_##r = F4C(dc_##r, ((KK) - (r)) & 3) + m_ + __logf(s_); \
    } while (0)

#define STORE(r) do { \
        const int j_ = jj - (r); \
        if (j_ >= 3 && j_ < MM) { \
            if (DIR) *(float4*)(stp_##r - j_) = \
                make_float4(np_##r, p1_##r, p2_##r, p3_##r); \
            else     *(float4*)(stp_##r + j_ - 3) = \
                make_float4(p3_##r, p2_##r, p1_##r, np_##r); \
        } \
    } while (0)

#define SHIFT(r) do { p3_##r = p2_##r; p2_##r = p1_##r; p1_##r = np_##r; } while (0)

#define STEP(KK, LA, LB, SA, SB) do { \
        const int jj = kbj + (KK); \
        SWAPLOAD(LA); SWAPLOAD(LB); \
        const float ups_ = wave_shr1(p1_7); \
        const float dgs_ = wave_shr1(p2_7); \
        const float up0r = l0 ? NEGV : ups_; \
        const float dg0r = l0 ? NEGV : dgs_; \
        CELL(0, KK, dg0r, up0r, dgb0); \
        CELL(1, KK, p2_0, p1_0, NEGV); \
        CELL(2, KK, p2_1, p1_1, NEGV); \
        CELL(3, KK, p2_2, p1_2, NEGV); \
        CELL(4, KK, p2_3, p1_3, NEGV); \
        CELL(5, KK, p2_4, p1_4, NEGV); \
        CELL(6, KK, p2_5, p1_5, NEGV); \
        CELL(7, KK, p2_6, p1_6, NEGV); \
        STORE(SA); STORE(SB); \
        SHIFT(0); SHIFT(1); SHIFT(2); SHIFT(3); \
        SHIFT(4); SHIFT(5); SHIFT(6); SHIFT(7); \
    } while (0)

    for (int kb = 0; kb < NN + MM; kb += 4) {
        const int kbj = kb - i0;
        STEP(0, 0, 4, 1, 5);
        STEP(1, 1, 5, 2, 6);
        STEP(2, 2, 6, 3, 7);
        STEP(3, 3, 7, 0, 4);
    }
#undef PTRS
#undef LOADG
#undef INIT
#undef SWAPLOAD
#undef CELL
#undef STORE
#undef SHIFT
#undef STEP
}

__global__ __launch_bounds__(64, 1) void dp_kernel_row(const float* __restrict__ D,
                                                       float* __restrict__ Rf,
                                                       float* __restrict__ Rb) {
    const int blk = blockIdx.x;
    const int b = blk & (BATCH - 1);
    const int dir = blk >> 6;
    const float* __restrict__ Db = D + (size_t)b * NM;
    const int lane = threadIdx.x;
    if (dir) dp_run_row<1>(Db, Rb + (size_t)b * NM, lane);
    else     dp_run_row<0>(Db, Rf + (size_t)b * NM, lane);
}

// ---------------------------------------------------------------------------
// tail kernels
// ---------------------------------------------------------------------------
__device__ inline float blockMax256(float v) {
    __shared__ float sm[256];
    sm[threadIdx.x] = v;
    __syncthreads();
    for (int s = 128; s > 0; s >>= 1) {
        if ((int)threadIdx.x < s)
            sm[threadIdx.x] = fmaxf(sm[threadIdx.x], sm[threadIdx.x + s]);
        __syncthreads();
    }
    return sm[0];
}

__global__ __launch_bounds__(256) void logit_kernel(const float4* __restrict__ D,
                                                    const float4* __restrict__ Rb,
                                                    float4* __restrict__ out,
                                                    float* __restrict__ partial) {
    const size_t n4 = TOTAL / 4;
    float mx = NEGV;
    const size_t stride = (size_t)gridDim.x * blockDim.x;
    for (size_t idx = (size_t)blockIdx.x * blockDim.x + threadIdx.x; idx < n4;
         idx += stride) {
        float4 f = out[idx], bb = Rb[idx], d = D[idx];
        float4 v = make_float4(f.x + bb.x - d.x, f.y + bb.y - d.y,
                               f.z + bb.z - d.z, f.w + bb.w - d.w);
        out[idx] = v;
        mx = fmaxf(mx, fmaxf(fmaxf(v.x, v.y), fmaxf(v.z, v.w)));
    }
    float bm = blockMax256(mx);
    if (threadIdx.x == 0) partial[blockIdx.x] = bm;
}

__global__ __launch_bounds__(256) void finalmax_kernel(const float* __restrict__ partial,
                                                       int n,
                                                       float* __restrict__ outmax) {
    float mx = NEGV;
    for (int i = threadIdx.x; i < n; i += 256) mx = fmaxf(mx, partial[i]);
    float bm = blockMax256(mx);
    if (threadIdx.x == 0) *outmax = bm;
}

__global__ __launch_bounds__(256) void sub_kernel(float4* __restrict__ out,
                                                  const float* __restrict__ maxp) {
    const float mx = *maxp;
    const size_t n4 = TOTAL / 4;
    const size_t stride = (size_t)gridDim.x * blockDim.x;
    for (size_t idx = (size_t)blockIdx.x * blockDim.x + threadIdx.x; idx < n4;
         idx += stride) {
        float4 v = out[idx];
        v.x -= mx; v.y -= mx; v.z -= mx; v.w -= mx;
        out[idx] = v;
    }
}

extern "C" void kernel_launch(void* const* d_in, const int* in_sizes, int n_in,
                              void* d_out, int out_size, void* d_ws, size_t ws_size,
                              hipStream_t stream) {
    const float* D = (const float*)d_in[0];
    float* out = (float*)d_out;           // Rf after K1, logit after K2
    float* ws_f = (float*)d_ws;
    float* Rb = ws_f;                     // 64 MB backward DP result
    float* partial = ws_f + TOTAL;        // 4096 floats (2048 used)
    float* maxp = partial + 4096;         // 1 float
    float* Dd = ws_f + TOTAL + 8192;      // diag-major D (dp over/under-run
                                          // is pre/post-padded: front covered
                                          // by partial region, back by +1024)
    const size_t need_f = TOTAL + 8192 + (size_t)BATCH * DBATCH + 1024;

    if (ws_size >= need_f * sizeof(float)) {
        restage_kernel<<<dim3(8, 8, 64), 256, 0, stream>>>(D, Dd);
        dp_kernel_diag<<<128, 64, 0, stream>>>(Dd, out, Rb);
    } else {
        dp_kernel_row<<<128, 64, 0, stream>>>(D, out, Rb);
    }
    logit_kernel<<<2048, 256, 0, stream>>>((const float4*)D, (const float4*)Rb,
                                           (float4*)out, partial);
    finalmax_kernel<<<1, 256, 0, stream>>>(partial, 2048, maxp);
    sub_kernel<<<2048, 256, 0, stream>>>((float4*)out, maxp);
}